// Round 8
// baseline (1468.758 us; speedup 1.0000x reference)
//
#include <hip/hip_runtime.h>
#include <math.h>

// B=64, S=256, IN_DIM=512, MEM=256, LAYERS=3, HEADS=8, TOP_K=200. NROW=16384.

typedef __attribute__((ext_vector_type(8))) short s16x8;
typedef __attribute__((ext_vector_type(4))) float f32x4;

__device__ __forceinline__ short f2bf(float x) {
    unsigned u = __float_as_uint(x);
    u += 0x7FFF + ((u >> 16) & 1);  // rn-even
    return (short)(u >> 16);
}
__device__ __forceinline__ float bf2f(short h) {
    return __uint_as_float(((unsigned)(unsigned short)h) << 16);
}

// async global->LDS, 16B per lane. LDS layout must be lane-contiguous (ours is).
__device__ __forceinline__ void gl2l(const void* g, void* l) {
    __builtin_amdgcn_global_load_lds(
        (const __attribute__((address_space(1))) unsigned int*)g,
        (__attribute__((address_space(3))) unsigned int*)l, 16, 0, 0);
}

__global__ void init_flags(int* flags) {
    if (threadIdx.x < 3) flags[threadIdx.x] = 0;
}

__global__ void detect_mask(const unsigned int* __restrict__ w, int nwords, int* flags) {
    int stride = gridDim.x * blockDim.x;
    int l_u8 = 0, l_f32 = 0, l_nz = 0;
    for (int i = blockIdx.x * blockDim.x + threadIdx.x; i < nwords; i += stride) {
        unsigned v = w[i];
        if (v) {
            l_nz = 1;
            if (v == 0x3F800000u) l_f32 = 1;
            else if (v > 1u) l_u8 = 1;
        }
    }
    if (__ballot(l_u8) && (threadIdx.x & 63) == 0) atomicOr(&flags[0], 1);
    if (__ballot(l_f32) && (threadIdx.x & 63) == 0) atomicOr(&flags[1], 1);
    if (__ballot(l_nz) && (threadIdx.x & 63) == 0) atomicOr(&flags[2], 1);
}

__global__ void extract_pad(const void* __restrict__ mask, const int* __restrict__ flags,
                            unsigned char* __restrict__ pad) {
    int b = blockIdx.x, i = threadIdx.x;
    int v;
    size_t idx = (size_t)b * 65536 + (size_t)i * 256;
    if (flags[0]) v = ((const unsigned char*)mask)[idx] != 0;
    else if (flags[2]) v = ((const unsigned int*)mask)[idx] != 0;
    else v = 0;
    pad[b * 256 + i] = (unsigned char)v;
}

// live[0]=count; live[1+i]=index of i-th live 128-row m-tile (pad is per-batch suffix).
__global__ void build_live(const unsigned char* __restrict__ pad, int* __restrict__ live) {
    if (threadIdx.x == 0) {
        int c = 0;
        for (int t = 0; t < 128; ++t)
            if (!pad[t * 128]) live[1 + c++] = t;
        live[0] = c;
    }
}

__global__ void split_mat(const float* __restrict__ src, int ldsrc, int width,
                          short* __restrict__ dh, short* __restrict__ dl, int ldd) {
    int row = blockIdx.x;
    for (int c = threadIdx.x; c < width; c += 256) {
        float v = src[(size_t)row * ldsrc + c];
        short h = f2bf(v);
        dh[(size_t)row * ldd + c] = h;
        dl[(size_t)row * ldd + c] = f2bf(v - bf2f(h));
    }
}

// Transposed split with half-pack: logical out-row orow -> buffer row
// (orow/HR)*PSTR + (orow%HR + rowoff), ld = outld.
__global__ void transpose_split(const float* __restrict__ in,
                                short* __restrict__ outh, short* __restrict__ outl,
                                int R, int C, int HR, long PSTR, int rowoff, int outld) {
    __shared__ float tile[32][33];
    int c0 = blockIdx.x * 32, r0 = blockIdx.y * 32;
    int tx = threadIdx.x & 31, ty = threadIdx.x >> 5;
    for (int rr = ty; rr < 32; rr += 8)
        tile[rr][tx] = in[(size_t)(r0 + rr) * C + c0 + tx];
    __syncthreads();
    for (int rr = ty; rr < 32; rr += 8) {
        float v = tile[tx][rr];
        int orow = c0 + rr;
        size_t o = (size_t)(orow / HR) * PSTR + (size_t)((orow % HR) + rowoff) * outld + (r0 + tx);
        short h = f2bf(v);
        outh[o] = h;
        outl[o] = f2bf(v - bf2f(h));
    }
}

__global__ void pack_bias2(const float* __restrict__ qb, const float* __restrict__ kb,
                           float* __restrict__ dst, int D) {
    int i = blockIdx.x * 256 + threadIdx.x;
    if (i < D) {
        int p = i / (D / 2), r = i % (D / 2);
        dst[(size_t)p * D + r] = qb[i];
        dst[(size_t)p * D + D / 2 + r] = kb[i];
    }
}

// Split-bf16 MFMA GEMM on pre-split inputs: acc = AhBh + AhBl + AlBh (fp32-class).
// A [M,K] lda, B [N,K] ldb (k-contiguous). 128x128 tile.
// swap: m-tile on blockIdx.x. skipmode 2: exit if padArr[zr*256+m0] or [zr*256+n0].
// skipmode 3: m-tile compaction via liveArr (exit if bx>=live[0], m0=live[1+bx]*128).
// o = alpha*acc + bias[ng]; writes C fp32 (offset zq*sC1+zr*sC2) and/or (Ch,Cl) split.
__global__ __launch_bounds__(256) void mgemm(
    const short* __restrict__ Ah, const short* __restrict__ Al,
    const short* __restrict__ Bh, const short* __restrict__ Bl,
    const float* __restrict__ bias,
    float* __restrict__ C, short* __restrict__ Ch, short* __restrict__ Cl,
    const unsigned char* __restrict__ padArr, const int* __restrict__ liveArr,
    int K, int lda, int ldb, int ldc, int coloff, int zdiv,
    long sA1, long sA2, long sB1, long sB2, long sC1, long sC2,
    float alpha, int skipmode, int swap) {
    int z = blockIdx.z, zq = z / zdiv, zr = z % zdiv;
    int m0, n0;
    if (swap) { m0 = blockIdx.x * 128; n0 = blockIdx.y * 128; }
    else      { m0 = blockIdx.y * 128; n0 = blockIdx.x * 128; }
    if (skipmode == 2 && (padArr[zr * 256 + m0] || padArr[zr * 256 + n0])) return;
    if (skipmode == 3) {
        int cnt = liveArr[0];
        if ((int)blockIdx.x >= cnt) return;
        m0 = liveArr[1 + blockIdx.x] * 128;
    }
    const short* Ahb = Ah + (size_t)zq * sA1 + (size_t)zr * sA2;
    const short* Alb = Al + (size_t)zq * sA1 + (size_t)zr * sA2;
    const short* Bhb = Bh + (size_t)zq * sB1 + (size_t)zr * sB2;
    const short* Blb = Bl + (size_t)zq * sB1 + (size_t)zr * sB2;
    size_t offC = (size_t)zq * sC1 + (size_t)zr * sC2;
    __shared__ short lds[16384];  // Ah[0:4096] Al[4096:] Bh[8192:] Bl[12288:]
    int t = threadIdx.x;
    int lane = t & 63, w = t >> 6;
    int wm = w >> 1, wn = w & 1;
    f32x4 acc[4][4];
#pragma unroll
    for (int i = 0; i < 4; ++i)
#pragma unroll
        for (int j = 0; j < 4; ++j)
            acc[i][j] = (f32x4){0.f, 0.f, 0.f, 0.f};

    for (int k0 = 0; k0 < K; k0 += 32) {
        __syncthreads();
#pragma unroll
        for (int p = 0; p < 2; ++p) {
            int s = t + p * 256;
            int mi = (s >> 6) * 16 + (s & 15);
            int koff = k0 + ((s >> 4) & 3) * 8;
            size_t oa = (size_t)(m0 + mi) * lda + koff;
            size_t ob = (size_t)(n0 + mi) * ldb + koff;
            gl2l(Ahb + oa, &lds[s * 8]);
            gl2l(Alb + oa, &lds[4096 + s * 8]);
            gl2l(Bhb + ob, &lds[8192 + s * 8]);
            gl2l(Blb + ob, &lds[12288 + s * 8]);
        }
        __syncthreads();
        s16x8 ah[4], al4[4], bh[4], bl4[4];
#pragma unroll
        for (int i = 0; i < 4; ++i) {
            int off = ((wm * 4 + i) * 64 + lane) * 8;
            ah[i] = *(const s16x8*)&lds[off];
            al4[i] = *(const s16x8*)&lds[4096 + off];
        }
#pragma unroll
        for (int j = 0; j < 4; ++j) {
            int off = ((wn * 4 + j) * 64 + lane) * 8;
            bh[j] = *(const s16x8*)&lds[8192 + off];
            bl4[j] = *(const s16x8*)&lds[12288 + off];
        }
#pragma unroll
        for (int i = 0; i < 4; ++i)
#pragma unroll
            for (int j = 0; j < 4; ++j) {
                acc[i][j] = __builtin_amdgcn_mfma_f32_16x16x32_bf16(ah[i], bh[j], acc[i][j], 0, 0, 0);
                acc[i][j] = __builtin_amdgcn_mfma_f32_16x16x32_bf16(ah[i], bl4[j], acc[i][j], 0, 0, 0);
                acc[i][j] = __builtin_amdgcn_mfma_f32_16x16x32_bf16(al4[i], bh[j], acc[i][j], 0, 0, 0);
            }
    }

    int col = lane & 15, quad = lane >> 4;
#pragma unroll
    for (int i = 0; i < 4; ++i)
#pragma unroll
        for (int j = 0; j < 4; ++j) {
            int mg = m0 + wm * 64 + i * 16 + quad * 4;
            int ng = n0 + wn * 64 + j * 16 + col;
            f32x4 v = acc[i][j];
            float bz = bias ? bias[ng] : 0.f;
            float o[4];
#pragma unroll
            for (int r = 0; r < 4; ++r) o[r] = v[r] * alpha + bz;
            if (C) {
                float* Cb = C + offC;
#pragma unroll
                for (int r = 0; r < 4; ++r)
                    Cb[(size_t)(mg + r) * ldc + coloff + ng] = o[r];
            }
            if (Ch) {
                short* Chb = Ch + offC;
                short* Clb = Cl + offC;
#pragma unroll
                for (int r = 0; r < 4; ++r) {
                    short hh = f2bf(o[r]);
                    Chb[(size_t)(mg + r) * ldc + coloff + ng] = hh;
                    Clb[(size_t)(mg + r) * ldc + coloff + ng] = f2bf(o[r] - bf2f(hh));
                }
            }
        }
}

// Fused SpMM + GCN epilogue. One wave per row i (batch b=i>>8):
//   acc[c] = sum_j A[i,j]*tz[b*256+j, c]   (exact fp32; zero entries skipped)
//   denom  = sum_j A[i,j] + 1
//   o[c]   = relu((acc[c]+bias[c])/denom) + tz[i,c] + bias[c]
// A is [16384,256] fp32 (adj input or a2). Write split (oh,ol)@coloff or fp32 of.
__global__ void spmm_gcn(const float* __restrict__ A, const float* __restrict__ tz,
                         const float* __restrict__ bias,
                         short* __restrict__ oh, short* __restrict__ ol,
                         float* __restrict__ of, int ldo, int coloff) {
    int row = blockIdx.x * 4 + (threadIdx.x >> 6);
    int lane = threadIdx.x & 63;
    int b = row >> 8;
    float4 av = ((const float4*)(A + (size_t)row * 256))[lane];
    const float* tzb = tz + (size_t)(b << 8) * 256;
    float4 acc = make_float4(0.f, 0.f, 0.f, 0.f);
    float rs = av.x + av.y + av.z + av.w;
#pragma unroll
    for (int o = 32; o; o >>= 1) rs += __shfl_xor(rs, o);
    for (int s = 0; s < 64; ++s) {
        float vx = __shfl(av.x, s), vy = __shfl(av.y, s);
        float vz = __shfl(av.z, s), vw = __shfl(av.w, s);
        const float* tj = tzb + (size_t)(s << 2) * 256;
        if (vx != 0.f) {
            float4 tv = ((const float4*)tj)[lane];
            acc.x += vx * tv.x; acc.y += vx * tv.y; acc.z += vx * tv.z; acc.w += vx * tv.w;
        }
        if (vy != 0.f) {
            float4 tv = ((const float4*)(tj + 256))[lane];
            acc.x += vy * tv.x; acc.y += vy * tv.y; acc.z += vy * tv.z; acc.w += vy * tv.w;
        }
        if (vz != 0.f) {
            float4 tv = ((const float4*)(tj + 512))[lane];
            acc.x += vz * tv.x; acc.y += vz * tv.y; acc.z += vz * tv.z; acc.w += vz * tv.w;
        }
        if (vw != 0.f) {
            float4 tv = ((const float4*)(tj + 768))[lane];
            acc.x += vw * tv.x; acc.y += vw * tv.y; acc.z += vw * tv.z; acc.w += vw * tv.w;
        }
    }
    float inv = 1.f / (rs + 1.f);
    float4 b4 = ((const float4*)bias)[lane];
    float4 t4 = ((const float4*)(tz + (size_t)row * 256))[lane];
    float4 o;
    o.x = fmaxf((acc.x + b4.x) * inv, 0.f) + t4.x + b4.x;
    o.y = fmaxf((acc.y + b4.y) * inv, 0.f) + t4.y + b4.y;
    o.z = fmaxf((acc.z + b4.z) * inv, 0.f) + t4.z + b4.z;
    o.w = fmaxf((acc.w + b4.w) * inv, 0.f) + t4.w + b4.w;
    if (of) {
        ((float4*)(of + (size_t)row * ldo))[lane] = o;
    } else {
        size_t base = (size_t)row * ldo + coloff + lane * 4;
        float vv[4] = {o.x, o.y, o.z, o.w};
#pragma unroll
        for (int r = 0; r < 4; ++r) {
            short hh = f2bf(vv[r]);
            oh[base + r] = hh;
            ol[base + r] = f2bf(vv[r] - bf2f(hh));
        }
    }
}

// Masked softmax for TWO heads (scores [2][64][256][256]); accumulates into a.
__global__ void softmax_headsum2(const float* __restrict__ scores,
                                 const unsigned char* __restrict__ pad,
                                 float* __restrict__ a, int accum) {
    int row = blockIdx.x * 4 + (threadIdx.x >> 6);
    int lane = threadIdx.x & 63;
    int b = row >> 8;
    float* arow = a + (size_t)row * 256;
    if (pad[row]) {
        if (!accum) ((float4*)arow)[lane] = make_float4(0.f, 0.f, 0.f, 0.f);
        return;
    }
    unsigned pw = *(const unsigned*)(pad + (b << 8) + lane * 4);
    float4 racc;
    if (accum) racc = ((float4*)arow)[lane];
    else racc = make_float4(0.f, 0.f, 0.f, 0.f);
#pragma unroll
    for (int hh = 0; hh < 2; ++hh) {
        float4 s = ((const float4*)(scores + (size_t)hh * 4194304 + (size_t)row * 256))[lane];
        if (pw & 0x000000FFu) s.x = -1e9f;
        if (pw & 0x0000FF00u) s.y = -1e9f;
        if (pw & 0x00FF0000u) s.z = -1e9f;
        if (pw & 0xFF000000u) s.w = -1e9f;
        float m = fmaxf(fmaxf(s.x, s.y), fmaxf(s.z, s.w));
#pragma unroll
        for (int o = 32; o; o >>= 1) m = fmaxf(m, __shfl_xor(m, o));
        float e0 = expf(s.x - m), e1 = expf(s.y - m), e2 = expf(s.z - m), e3 = expf(s.w - m);
        float sum = e0 + e1 + e2 + e3;
#pragma unroll
        for (int o = 32; o; o >>= 1) sum += __shfl_xor(sum, o);
        float inv = 1.f / sum;
        racc.x += e0 * inv; racc.y += e1 * inv; racc.z += e2 * inv; racc.w += e3 * inv;
    }
    ((float4*)arow)[lane] = racc;
}

// ---- parallel exact top-200 radix select
__global__ void tk_init(unsigned* ghist, unsigned* prefix, int* krem) {
    int i = blockIdx.x * 256 + threadIdx.x;
    ghist[i] = 0;
    if (i < 64) { prefix[i] = 0; krem[i] = 200; }
}

__global__ void tk_hist(const float* __restrict__ a, const unsigned* __restrict__ prefix,
                        unsigned* __restrict__ ghist, int shift) {
    __shared__ unsigned h[256];
    int b = blockIdx.x >> 4, slice = blockIdx.x & 15;
    h[threadIdx.x] = 0;
    __syncthreads();
    unsigned pfx = prefix[b];
    const unsigned* ab = (const unsigned*)(a + (size_t)b * 65536) + slice * 4096;
    for (int i = threadIdx.x; i < 4096; i += 256) {
        unsigned u = ab[i];
        if ((shift == 24) || ((u >> (shift + 8)) == pfx)) atomicAdd(&h[(u >> shift) & 255], 1u);
    }
    __syncthreads();
    if (h[threadIdx.x]) atomicAdd(&ghist[b * 256 + threadIdx.x], h[threadIdx.x]);
}

__global__ void tk_pick(unsigned* __restrict__ ghist, unsigned* __restrict__ prefix,
                        int* __restrict__ krem, float* __restrict__ thr, int last) {
    __shared__ unsigned h[256];
    int b = blockIdx.x;
    h[threadIdx.x] = ghist[b * 256 + threadIdx.x];
    ghist[b * 256 + threadIdx.x] = 0;
    __syncthreads();
    if (!threadIdx.x) {
        int k = krem[b];
        unsigned c = 0;
        int bin = 255;
        for (; bin >= 0; --bin) { c += h[bin]; if ((int)c >= k) break; }
        if (bin < 0) bin = 0;
        krem[b] = k - (int)(c - h[bin]);
        unsigned p = (prefix[b] << 8) | (unsigned)bin;
        prefix[b] = p;
        if (last) thr[b] = __uint_as_float(p);
    }
}

// a2 = a * (sel + sel^T off-diag, 1 on diag), fp32
__global__ void select_apply(const float* __restrict__ a, const float* __restrict__ thr,
                             float* __restrict__ a2) {
    int row = blockIdx.x;
    int b = row >> 8, i = row & 255, j = threadIdx.x;
    const float* ab = a + (size_t)b * 65536;
    float tb = thr[b];
    float v = ab[i * 256 + j];
    float vt = ab[j * 256 + i];
    float sel = (v >= tb ? 1.f : 0.f) + (vt >= tb ? 1.f : 0.f);
    if (i == j) sel = 1.f;
    a2[(size_t)row * 256 + j] = v * sel;
}

extern "C" void kernel_launch(void* const* d_in, const int* in_sizes, int n_in,
                              void* d_out, int out_size, void* d_ws, size_t ws_size,
                              hipStream_t stream) {
    const float* adj = (const float*)d_in[0];
    const float* x0 = (const float*)d_in[1];
    const void* mask = d_in[2];
    const float* Wls[3] = {(const float*)d_in[3], (const float*)d_in[5], (const float*)d_in[7]};
    const float* bls[3] = {(const float*)d_in[4], (const float*)d_in[6], (const float*)d_in[8]};
    const float* qws[2] = {(const float*)d_in[9], (const float*)d_in[13]};
    const float* qbs[2] = {(const float*)d_in[10], (const float*)d_in[14]};
    const float* kws[2] = {(const float*)d_in[11], (const float*)d_in[15]};
    const float* kbs[2] = {(const float*)d_in[12], (const float*)d_in[16]};

    char* base = (char*)d_ws;
    size_t cur = 0;
    auto alloc = [&](size_t bytes) -> void* {
        cur = (cur + 1023) & ~(size_t)1023;
        void* p = base + cur;
        cur += bytes;
        return p;
    };
    const size_t NROW = 16384;
    int* flags = (int*)alloc(12);
    unsigned char* pad = (unsigned char*)alloc(NROW);
    float* thr = (float*)alloc(256);
    unsigned* prefix = (unsigned*)alloc(256);
    int* krem = (int*)alloc(256);
    int* live = (int*)alloc(516);
    unsigned* ghist = (unsigned*)alloc(64 * 256 * 4);
    short* WTh = (short*)alloc((size_t)2304 * 256 * 2);
    short* WTl = (short*)alloc((size_t)2304 * 256 * 2);
    short* qkwPh = (short*)alloc((size_t)2 * 1024 * 1024 * 2);  // [half p][D rows][D]
    short* qkwPl = (short*)alloc((size_t)2 * 1024 * 1024 * 2);
    float* qkb = (float*)alloc((size_t)2 * 1024 * 4);
    short* xh = (short*)alloc(NROW * 1024 * 2);
    short* xl = (short*)alloc(NROW * 1024 * 2);
    float* tzf = (float*)alloc(NROW * 256 * 4);     // x@W fp32 row-major
    float* scores = (float*)alloc((size_t)2 * 64 * 65536 * 4);  // 2 heads
    float* a = (float*)alloc(NROW * 256 * 4);
    float* a2f = (float*)alloc(NROW * 256 * 4);
    short* QKh = (short*)alloc(NROW * 1024 * 2);    // half-heads Q|K [16384, D]
    short* QKl = (short*)alloc(NROW * 1024 * 2);
    if (ws_size < cur) return;  // clean failure instead of device fault

    const int Ks[3] = {512, 768, 1024};
    const long offW[3] = {0, (long)512 * 256, (long)(512 + 768) * 256};

    init_flags<<<1, 64, 0, stream>>>(flags);
    detect_mask<<<64, 256, 0, stream>>>((const unsigned int*)mask, 1048576, flags);
    extract_pad<<<64, 256, 0, stream>>>(mask, flags, pad);
    build_live<<<1, 64, 0, stream>>>(pad, live);
    split_mat<<<16384, 256, 0, stream>>>(x0, 512, 512, xh, xl, 1024);
    for (int l = 0; l < 3; ++l)
        transpose_split<<<dim3(8, Ks[l] / 32), 256, 0, stream>>>(
            Wls[l], WTh + offW[l], WTl + offW[l], Ks[l], 256, 256, 0, 0, Ks[l]);

    for (int l = 0; l < 3; ++l) {
        int Kl = Ks[l];
        // tzf = x @ Wl (fp32 row-major, no bias; bias applied in spmm epilogue)
        mgemm<<<dim3(128, 2, 1), 256, 0, stream>>>(
            xh, xl, WTh + offW[l], WTl + offW[l], nullptr,
            tzf, nullptr, nullptr, nullptr, nullptr,
            Kl, 1024, Kl, 256, 0, 1,
            0, 0, 0, 0, 0, 0, 1.f, 0, 1);
        // fused sparse GCN: out = relu((A@tz + b)/denom) + tz + b   (exact fp32)
        const float* Aadj = (l == 0) ? adj : a2f;
        if (l < 2) {
            spmm_gcn<<<4096, 256, 0, stream>>>(
                Aadj, tzf, bls[l], xh, xl, nullptr, 1024, Kl);
        } else {
            spmm_gcn<<<4096, 256, 0, stream>>>(
                Aadj, tzf, bls[l], nullptr, nullptr, (float*)d_out, 256, 0);
            break;
        }

        // ---- attention l (D = Ks[l+1], dk = D/8), two head-halves of 4 heads
        int D = Ks[l + 1], dk = D / 8, HD = D / 2;
        float scale = 1.f / sqrtf((float)dk);
        // packed weights: [p][0:HD]=Wq^T half p, [p][HD:D]=Wk^T half p
        transpose_split<<<dim3(D / 32, D / 32), 256, 0, stream>>>(
            qws[l], qkwPh, qkwPl, D, D, HD, (long)D * D, 0, D);
        transpose_split<<<dim3(D / 32, D / 32), 256, 0, stream>>>(
            kws[l], qkwPh, qkwPl, D, D, HD, (long)D * D, HD, D);
        pack_bias2<<<4, 256, 0, stream>>>(qbs[l], kbs[l], qkb, D);

        for (int p = 0; p < 2; ++p) {
            // QK[:,0:HD]=Q(4 heads), QK[:,HD:D]=K(4 heads): one dispatch, N=D.
            // live-compacted m-tiles: balanced across CUs.
            mgemm<<<dim3(128, D / 128, 1), 256, 0, stream>>>(
                xh, xl, qkwPh + (size_t)p * D * D, qkwPl + (size_t)p * D * D, qkb + (size_t)p * D,
                nullptr, QKh, QKl, nullptr, live,
                D, 1024, D, D, 0, 1,
                0, 0, 0, 0, 0, 0, 1.f, 3, 1);
            for (int hp = 0; hp < 2; ++hp) {  // 2 heads per scores dispatch
                mgemm<<<dim3(2, 2, 128), 256, 0, stream>>>(
                    QKh + (size_t)(hp * 2) * dk, QKl + (size_t)(hp * 2) * dk,
                    QKh + HD + (size_t)(hp * 2) * dk, QKl + HD + (size_t)(hp * 2) * dk,
                    nullptr, scores, nullptr, nullptr, pad, nullptr,
                    dk, D, D, 256, 0, 64,
                    dk, (long)256 * D, dk, (long)256 * D, (long)64 * 65536, 65536,
                    scale, 2, 0);
                softmax_headsum2<<<4096, 256, 0, stream>>>(scores, pad, a, (p * 2 + hp) ? 1 : 0);
            }
        }
        tk_init<<<64, 256, 0, stream>>>(ghist, prefix, krem);
        for (int pp = 0; pp < 4; ++pp) {
            tk_hist<<<1024, 256, 0, stream>>>(a, prefix, ghist, 24 - 8 * pp);
            tk_pick<<<64, 256, 0, stream>>>(ghist, prefix, krem, thr, pp == 3);
        }
        select_apply<<<16384, 256, 0, stream>>>(a, thr, a2f);
    }
}

// Round 9
// 1383.990 us; speedup vs baseline: 1.0612x; 1.0612x over previous
//
#include <hip/hip_runtime.h>
#include <math.h>

// B=64, S=256, IN_DIM=512, MEM=256, LAYERS=3, HEADS=8, TOP_K=200. NROW=16384.

typedef __attribute__((ext_vector_type(8))) short s16x8;
typedef __attribute__((ext_vector_type(4))) float f32x4;

__device__ __forceinline__ short f2bf(float x) {
    unsigned u = __float_as_uint(x);
    u += 0x7FFF + ((u >> 16) & 1);  // rn-even
    return (short)(u >> 16);
}
__device__ __forceinline__ float bf2f(short h) {
    return __uint_as_float(((unsigned)(unsigned short)h) << 16);
}

// async global->LDS, 16B per lane. LDS layout must be lane-contiguous (ours is).
__device__ __forceinline__ void gl2l(const void* g, void* l) {
    __builtin_amdgcn_global_load_lds(
        (const __attribute__((address_space(1))) unsigned int*)g,
        (__attribute__((address_space(3))) unsigned int*)l, 16, 0, 0);
}

__global__ void init_flags(int* flags) {
    if (threadIdx.x < 3) flags[threadIdx.x] = 0;
}

__global__ void detect_mask(const unsigned int* __restrict__ w, int nwords, int* flags) {
    int stride = gridDim.x * blockDim.x;
    int l_u8 = 0, l_f32 = 0, l_nz = 0;
    for (int i = blockIdx.x * blockDim.x + threadIdx.x; i < nwords; i += stride) {
        unsigned v = w[i];
        if (v) {
            l_nz = 1;
            if (v == 0x3F800000u) l_f32 = 1;
            else if (v > 1u) l_u8 = 1;
        }
    }
    if (__ballot(l_u8) && (threadIdx.x & 63) == 0) atomicOr(&flags[0], 1);
    if (__ballot(l_f32) && (threadIdx.x & 63) == 0) atomicOr(&flags[1], 1);
    if (__ballot(l_nz) && (threadIdx.x & 63) == 0) atomicOr(&flags[2], 1);
}

__global__ void extract_pad(const void* __restrict__ mask, const int* __restrict__ flags,
                            unsigned char* __restrict__ pad) {
    int b = blockIdx.x, i = threadIdx.x;
    int v;
    size_t idx = (size_t)b * 65536 + (size_t)i * 256;
    if (flags[0]) v = ((const unsigned char*)mask)[idx] != 0;
    else if (flags[2]) v = ((const unsigned int*)mask)[idx] != 0;
    else v = 0;
    pad[b * 256 + i] = (unsigned char)v;
}

__global__ void split_mat(const float* __restrict__ src, int ldsrc, int width,
                          short* __restrict__ dh, short* __restrict__ dl, int ldd) {
    int row = blockIdx.x;
    for (int c = threadIdx.x; c < width; c += 256) {
        float v = src[(size_t)row * ldsrc + c];
        short h = f2bf(v);
        dh[(size_t)row * ldd + c] = h;
        dl[(size_t)row * ldd + c] = f2bf(v - bf2f(h));
    }
}

// Transposed split with half-pack: logical out-row orow -> buffer row
// (orow/HR)*PSTR + (orow%HR + rowoff), ld = outld.
__global__ void transpose_split(const float* __restrict__ in,
                                short* __restrict__ outh, short* __restrict__ outl,
                                int R, int C, int HR, long PSTR, int rowoff, int outld) {
    __shared__ float tile[32][33];
    int c0 = blockIdx.x * 32, r0 = blockIdx.y * 32;
    int tx = threadIdx.x & 31, ty = threadIdx.x >> 5;
    for (int rr = ty; rr < 32; rr += 8)
        tile[rr][tx] = in[(size_t)(r0 + rr) * C + c0 + tx];
    __syncthreads();
    for (int rr = ty; rr < 32; rr += 8) {
        float v = tile[tx][rr];
        int orow = c0 + rr;
        size_t o = (size_t)(orow / HR) * PSTR + (size_t)((orow % HR) + rowoff) * outld + (r0 + tx);
        short h = f2bf(v);
        outh[o] = h;
        outl[o] = f2bf(v - bf2f(h));
    }
}

__global__ void pack_bias2(const float* __restrict__ qb, const float* __restrict__ kb,
                           float* __restrict__ dst, int D) {
    int i = blockIdx.x * 256 + threadIdx.x;
    if (i < D) {
        int p = i / (D / 2), r = i % (D / 2);
        dst[(size_t)p * D + r] = qb[i];
        dst[(size_t)p * D + D / 2 + r] = kb[i];
    }
}

// Split-bf16 MFMA GEMM on pre-split inputs: acc = AhBh + AhBl + AlBh (fp32-class).
// A [M,K] lda, B [N,K] ldb (k-contiguous). 128x128 tile, m-tile on blockIdx.x.
// padArr non-null: skip tile if padArr[m0] (pad is a per-batch suffix).
// o = acc + bias[ng]; writes C fp32 (ldc) or (Ch,Cl) split (ldc).
__global__ __launch_bounds__(256) void mgemm(
    const short* __restrict__ Ah, const short* __restrict__ Al,
    const short* __restrict__ Bh, const short* __restrict__ Bl,
    const float* __restrict__ bias,
    float* __restrict__ C, short* __restrict__ Ch, short* __restrict__ Cl,
    const unsigned char* __restrict__ padArr,
    int K, int lda, int ldb, int ldc) {
    int m0 = blockIdx.x * 128, n0 = blockIdx.y * 128;
    if (padArr && padArr[m0]) return;
    __shared__ short lds[16384];  // Ah[0:4096] Al[4096:] Bh[8192:] Bl[12288:]
    int t = threadIdx.x;
    int lane = t & 63, w = t >> 6;
    int wm = w >> 1, wn = w & 1;
    f32x4 acc[4][4];
#pragma unroll
    for (int i = 0; i < 4; ++i)
#pragma unroll
        for (int j = 0; j < 4; ++j)
            acc[i][j] = (f32x4){0.f, 0.f, 0.f, 0.f};

    for (int k0 = 0; k0 < K; k0 += 32) {
        __syncthreads();
#pragma unroll
        for (int p = 0; p < 2; ++p) {
            int s = t + p * 256;
            int mi = (s >> 6) * 16 + (s & 15);
            int koff = k0 + ((s >> 4) & 3) * 8;
            size_t oa = (size_t)(m0 + mi) * lda + koff;
            size_t ob = (size_t)(n0 + mi) * ldb + koff;
            gl2l(Ah + oa, &lds[s * 8]);
            gl2l(Al + oa, &lds[4096 + s * 8]);
            gl2l(Bh + ob, &lds[8192 + s * 8]);
            gl2l(Bl + ob, &lds[12288 + s * 8]);
        }
        __syncthreads();
        s16x8 ah[4], al4[4], bh[4], bl4[4];
#pragma unroll
        for (int i = 0; i < 4; ++i) {
            int off = ((wm * 4 + i) * 64 + lane) * 8;
            ah[i] = *(const s16x8*)&lds[off];
            al4[i] = *(const s16x8*)&lds[4096 + off];
        }
#pragma unroll
        for (int j = 0; j < 4; ++j) {
            int off = ((wn * 4 + j) * 64 + lane) * 8;
            bh[j] = *(const s16x8*)&lds[8192 + off];
            bl4[j] = *(const s16x8*)&lds[12288 + off];
        }
#pragma unroll
        for (int i = 0; i < 4; ++i)
#pragma unroll
            for (int j = 0; j < 4; ++j) {
                acc[i][j] = __builtin_amdgcn_mfma_f32_16x16x32_bf16(ah[i], bh[j], acc[i][j], 0, 0, 0);
                acc[i][j] = __builtin_amdgcn_mfma_f32_16x16x32_bf16(ah[i], bl4[j], acc[i][j], 0, 0, 0);
                acc[i][j] = __builtin_amdgcn_mfma_f32_16x16x32_bf16(al4[i], bh[j], acc[i][j], 0, 0, 0);
            }
    }

    int col = lane & 15, quad = lane >> 4;
#pragma unroll
    for (int i = 0; i < 4; ++i)
#pragma unroll
        for (int j = 0; j < 4; ++j) {
            int mg = m0 + wm * 64 + i * 16 + quad * 4;
            int ng = n0 + wn * 64 + j * 16 + col;
            f32x4 v = acc[i][j];
            float bz = bias ? bias[ng] : 0.f;
            float o[4];
#pragma unroll
            for (int r = 0; r < 4; ++r) o[r] = v[r] + bz;
            if (C) {
#pragma unroll
                for (int r = 0; r < 4; ++r)
                    C[(size_t)(mg + r) * ldc + ng] = o[r];
            } else {
#pragma unroll
                for (int r = 0; r < 4; ++r) {
                    short hh = f2bf(o[r]);
                    Ch[(size_t)(mg + r) * ldc + ng] = hh;
                    Cl[(size_t)(mg + r) * ldc + ng] = f2bf(o[r] - bf2f(hh));
                }
            }
        }
}

// Fused SpMM + GCN epilogue. One wave per row i (batch b=i>>8):
//   acc[c] = sum_j A[i,j]*tz[b*256+j, c]; denom = sum_j A[i,j] + 1
//   o[c]   = relu((acc[c]+bias[c])/denom) + tz[i,c] + bias[c]
__global__ void spmm_gcn(const float* __restrict__ A, const float* __restrict__ tz,
                         const float* __restrict__ bias,
                         short* __restrict__ oh, short* __restrict__ ol,
                         float* __restrict__ of, int ldo, int coloff) {
    int row = blockIdx.x * 4 + (threadIdx.x >> 6);
    int lane = threadIdx.x & 63;
    int b = row >> 8;
    float4 av = ((const float4*)(A + (size_t)row * 256))[lane];
    const float* tzb = tz + (size_t)(b << 8) * 256;
    float4 acc = make_float4(0.f, 0.f, 0.f, 0.f);
    float rs = av.x + av.y + av.z + av.w;
#pragma unroll
    for (int o = 32; o; o >>= 1) rs += __shfl_xor(rs, o);
    for (int s = 0; s < 64; ++s) {
        float vx = __shfl(av.x, s), vy = __shfl(av.y, s);
        float vz = __shfl(av.z, s), vw = __shfl(av.w, s);
        const float* tj = tzb + (size_t)(s << 2) * 256;
        if (vx != 0.f) {
            float4 tv = ((const float4*)tj)[lane];
            acc.x += vx * tv.x; acc.y += vx * tv.y; acc.z += vx * tv.z; acc.w += vx * tv.w;
        }
        if (vy != 0.f) {
            float4 tv = ((const float4*)(tj + 256))[lane];
            acc.x += vy * tv.x; acc.y += vy * tv.y; acc.z += vy * tv.z; acc.w += vy * tv.w;
        }
        if (vz != 0.f) {
            float4 tv = ((const float4*)(tj + 512))[lane];
            acc.x += vz * tv.x; acc.y += vz * tv.y; acc.z += vz * tv.z; acc.w += vz * tv.w;
        }
        if (vw != 0.f) {
            float4 tv = ((const float4*)(tj + 768))[lane];
            acc.x += vw * tv.x; acc.y += vw * tv.y; acc.z += vw * tv.z; acc.w += vw * tv.w;
        }
    }
    float inv = 1.f / (rs + 1.f);
    float4 b4 = ((const float4*)bias)[lane];
    float4 t4 = ((const float4*)(tz + (size_t)row * 256))[lane];
    float4 o;
    o.x = fmaxf((acc.x + b4.x) * inv, 0.f) + t4.x + b4.x;
    o.y = fmaxf((acc.y + b4.y) * inv, 0.f) + t4.y + b4.y;
    o.z = fmaxf((acc.z + b4.z) * inv, 0.f) + t4.z + b4.z;
    o.w = fmaxf((acc.w + b4.w) * inv, 0.f) + t4.w + b4.w;
    if (of) {
        ((float4*)(of + (size_t)row * ldo))[lane] = o;
    } else {
        size_t base = (size_t)row * ldo + coloff + lane * 4;
        float vv[4] = {o.x, o.y, o.z, o.w};
#pragma unroll
        for (int r = 0; r < 4; ++r) {
            short hh = f2bf(vv[r]);
            oh[base + r] = hh;
            ol[base + r] = f2bf(vv[r] - bf2f(hh));
        }
    }
}

// Fused flash-style scores+softmax+head-pair-sum. Grid (4 m-tiles of 64, 64 batches,
// 2 head-pairs). Reads one QK half (Q cols [0,HD), K cols [HD,D)); writes
// a4[z] = sum of 2 heads' softmax rows (fp32). Pad rows in live tiles -> exact 0.
__global__ __launch_bounds__(256) void attn_fused(
    const short* __restrict__ QKh, const short* __restrict__ QKl,
    const unsigned char* __restrict__ pad, float* __restrict__ a4,
    int D, int dk, float scale) {
    int HD = D / 2;
    int b = blockIdx.y;
    int m0 = blockIdx.x * 64;
    const unsigned char* pb = pad + (b << 8);
    if (pb[m0]) return;
    int t = threadIdx.x, lane = t & 63, w = t >> 6;
    int wm = w >> 1, wn = w & 1;
    int col16 = lane & 15, quad = lane >> 4;
    __shared__ short lds[20480];  // Qh[0,2048) Ql[2048,4096) Kh[4096,12288) Kl[12288,20480)
    __shared__ float redm[64][2];
    __shared__ float reds[64][2];
    unsigned cmask = 0;
#pragma unroll
    for (int j = 0; j < 8; ++j)
        if (pb[wn * 128 + j * 16 + col16]) cmask |= 1u << j;
    float* a4b = a4 + (size_t)blockIdx.z * 4194304;
    size_t rowQ = (size_t)(b << 8) + m0;
    size_t rowK = (size_t)(b << 8);
    float aacc[2][8][4];
#pragma unroll
    for (int i = 0; i < 2; ++i)
#pragma unroll
        for (int j = 0; j < 8; ++j)
#pragma unroll
            for (int r = 0; r < 4; ++r) aacc[i][j][r] = 0.f;

    for (int hh = 0; hh < 2; ++hh) {
        int hs = blockIdx.z * 2 + hh;
        int qo = hs * dk, ko = HD + hs * dk;
        f32x4 acc[2][8];
#pragma unroll
        for (int i = 0; i < 2; ++i)
#pragma unroll
            for (int j = 0; j < 8; ++j) acc[i][j] = (f32x4){0.f, 0.f, 0.f, 0.f};
        for (int k0 = 0; k0 < dk; k0 += 32) {
            __syncthreads();
            {
                int mi = ((t >> 6) << 4) + (t & 15);
                int kc = ((t >> 4) & 3) << 3;
                size_t o = (rowQ + mi) * D + qo + k0 + kc;
                gl2l(QKh + o, &lds[t * 8]);
                gl2l(QKl + o, &lds[2048 + t * 8]);
            }
#pragma unroll
            for (int kk = 0; kk < 4; ++kk) {
                int s = t + (kk << 8);
                int ni = ((s >> 6) << 4) + (s & 15);
                int kc = ((s >> 4) & 3) << 3;
                size_t o = (rowK + ni) * D + ko + k0 + kc;
                gl2l(QKh + o, &lds[4096 + s * 8]);
                gl2l(QKl + o, &lds[12288 + s * 8]);
            }
            __syncthreads();
            s16x8 qh[2], ql[2];
#pragma unroll
            for (int i = 0; i < 2; ++i) {
                int off = ((wm * 2 + i) * 64 + lane) * 8;
                qh[i] = *(const s16x8*)&lds[off];
                ql[i] = *(const s16x8*)&lds[2048 + off];
            }
#pragma unroll
            for (int j = 0; j < 8; ++j) {
                int off = ((wn * 8 + j) * 64 + lane) * 8;
                s16x8 kh = *(const s16x8*)&lds[4096 + off];
                s16x8 kl = *(const s16x8*)&lds[12288 + off];
#pragma unroll
                for (int i = 0; i < 2; ++i) {
                    acc[i][j] = __builtin_amdgcn_mfma_f32_16x16x32_bf16(qh[i], kh, acc[i][j], 0, 0, 0);
                    acc[i][j] = __builtin_amdgcn_mfma_f32_16x16x32_bf16(qh[i], kl, acc[i][j], 0, 0, 0);
                    acc[i][j] = __builtin_amdgcn_mfma_f32_16x16x32_bf16(ql[i], kh, acc[i][j], 0, 0, 0);
                }
            }
        }
        // masked softmax over full 256 cols (cross-wave via LDS), head-sum into aacc
        float rmax[2][4];
#pragma unroll
        for (int i = 0; i < 2; ++i)
#pragma unroll
            for (int r = 0; r < 4; ++r) rmax[i][r] = -1e30f;
#pragma unroll
        for (int i = 0; i < 2; ++i)
#pragma unroll
            for (int j = 0; j < 8; ++j) {
                bool msk = (cmask >> j) & 1;
#pragma unroll
                for (int r = 0; r < 4; ++r) {
                    float v = msk ? -1e30f : acc[i][j][r] * scale;
                    acc[i][j][r] = v;
                    rmax[i][r] = fmaxf(rmax[i][r], v);
                }
            }
#pragma unroll
        for (int ms = 1; ms < 16; ms <<= 1)
#pragma unroll
            for (int i = 0; i < 2; ++i)
#pragma unroll
                for (int r = 0; r < 4; ++r)
                    rmax[i][r] = fmaxf(rmax[i][r], __shfl_xor(rmax[i][r], ms));
        if (col16 == 0)
#pragma unroll
            for (int i = 0; i < 2; ++i)
#pragma unroll
                for (int r = 0; r < 4; ++r)
                    redm[wm * 32 + i * 16 + quad * 4 + r][wn] = rmax[i][r];
        __syncthreads();
#pragma unroll
        for (int i = 0; i < 2; ++i)
#pragma unroll
            for (int r = 0; r < 4; ++r) {
                int rr = wm * 32 + i * 16 + quad * 4 + r;
                rmax[i][r] = fmaxf(redm[rr][0], redm[rr][1]);
            }
        float rsum[2][4];
#pragma unroll
        for (int i = 0; i < 2; ++i)
#pragma unroll
            for (int r = 0; r < 4; ++r) rsum[i][r] = 0.f;
#pragma unroll
        for (int i = 0; i < 2; ++i)
#pragma unroll
            for (int j = 0; j < 8; ++j) {
                bool msk = (cmask >> j) & 1;
#pragma unroll
                for (int r = 0; r < 4; ++r) {
                    float p = msk ? 0.f : __expf(acc[i][j][r] - rmax[i][r]);
                    acc[i][j][r] = p;
                    rsum[i][r] += p;
                }
            }
#pragma unroll
        for (int ms = 1; ms < 16; ms <<= 1)
#pragma unroll
            for (int i = 0; i < 2; ++i)
#pragma unroll
                for (int r = 0; r < 4; ++r)
                    rsum[i][r] += __shfl_xor(rsum[i][r], ms);
        if (col16 == 0)
#pragma unroll
            for (int i = 0; i < 2; ++i)
#pragma unroll
                for (int r = 0; r < 4; ++r)
                    reds[wm * 32 + i * 16 + quad * 4 + r][wn] = rsum[i][r];
        __syncthreads();
#pragma unroll
        for (int i = 0; i < 2; ++i)
#pragma unroll
            for (int r = 0; r < 4; ++r) {
                int rr = wm * 32 + i * 16 + quad * 4 + r;
                float tot = reds[rr][0] + reds[rr][1];
                float inv = tot > 0.f ? 1.f / tot : 0.f;
#pragma unroll
                for (int j = 0; j < 8; ++j)
                    aacc[i][j][r] += acc[i][j][r] * inv;
            }
    }
#pragma unroll
    for (int i = 0; i < 2; ++i)
#pragma unroll
        for (int r = 0; r < 4; ++r) {
            size_t rb = (rowQ + wm * 32 + i * 16 + quad * 4 + r) * 256;
#pragma unroll
            for (int j = 0; j < 8; ++j)
                a4b[rb + wn * 128 + j * 16 + col16] = aacc[i][j][r];
        }
}

// a = sum of 4 partials (0 for pad rows). a aliases a4[0] (read-before-write per thread).
__global__ void add4(const float* __restrict__ a4, const unsigned char* __restrict__ pad,
                     float* __restrict__ a) {
    int row = blockIdx.x * 4 + (threadIdx.x >> 6);
    int lane = threadIdx.x & 63;
    size_t o = (size_t)row * 256 + lane * 4;
    float4 s = make_float4(0.f, 0.f, 0.f, 0.f);
    if (!pad[row]) {
#pragma unroll
        for (int z = 0; z < 4; ++z) {
            float4 v = *(const float4*)(a4 + (size_t)z * 4194304 + o);
            s.x += v.x; s.y += v.y; s.z += v.z; s.w += v.w;
        }
    }
    *(float4*)(a + o) = s;
}

// ---- parallel exact top-200 radix select
__global__ void tk_init(unsigned* ghist, unsigned* prefix, int* krem) {
    int i = blockIdx.x * 256 + threadIdx.x;
    ghist[i] = 0;
    if (i < 64) { prefix[i] = 0; krem[i] = 200; }
}

__global__ void tk_hist(const float* __restrict__ a, const unsigned* __restrict__ prefix,
                        unsigned* __restrict__ ghist, int shift) {
    __shared__ unsigned h[256];
    int b = blockIdx.x >> 4, slice = blockIdx.x & 15;
    h[threadIdx.x] = 0;
    __syncthreads();
    unsigned pfx = prefix[b];
    const unsigned* ab = (const unsigned*)(a + (size_t)b * 65536) + slice * 4096;
    for (int i = threadIdx.x; i < 4096; i += 256) {
        unsigned u = ab[i];
        if ((shift == 24) || ((u >> (shift + 8)) == pfx)) atomicAdd(&h[(u >> shift) & 255], 1u);
    }
    __syncthreads();
    if (h[threadIdx.x]) atomicAdd(&ghist[b * 256 + threadIdx.x], h[threadIdx.x]);
}

__global__ void tk_pick(unsigned* __restrict__ ghist, unsigned* __restrict__ prefix,
                        int* __restrict__ krem, float* __restrict__ thr, int last) {
    __shared__ unsigned h[256];
    int b = blockIdx.x;
    h[threadIdx.x] = ghist[b * 256 + threadIdx.x];
    ghist[b * 256 + threadIdx.x] = 0;
    __syncthreads();
    if (!threadIdx.x) {
        int k = krem[b];
        unsigned c = 0;
        int bin = 255;
        for (; bin >= 0; --bin) { c += h[bin]; if ((int)c >= k) break; }
        if (bin < 0) bin = 0;
        krem[b] = k - (int)(c - h[bin]);
        unsigned p = (prefix[b] << 8) | (unsigned)bin;
        prefix[b] = p;
        if (last) thr[b] = __uint_as_float(p);
    }
}

// a2 = a * (sel + sel^T off-diag, 1 on diag), fp32
__global__ void select_apply(const float* __restrict__ a, const float* __restrict__ thr,
                             float* __restrict__ a2) {
    int row = blockIdx.x;
    int b = row >> 8, i = row & 255, j = threadIdx.x;
    const float* ab = a + (size_t)b * 65536;
    float tb = thr[b];
    float v = ab[i * 256 + j];
    float vt = ab[j * 256 + i];
    float sel = (v >= tb ? 1.f : 0.f) + (vt >= tb ? 1.f : 0.f);
    if (i == j) sel = 1.f;
    a2[(size_t)row * 256 + j] = v * sel;
}

extern "C" void kernel_launch(void* const* d_in, const int* in_sizes, int n_in,
                              void* d_out, int out_size, void* d_ws, size_t ws_size,
                              hipStream_t stream) {
    const float* adj = (const float*)d_in[0];
    const float* x0 = (const float*)d_in[1];
    const void* mask = d_in[2];
    const float* Wls[3] = {(const float*)d_in[3], (const float*)d_in[5], (const float*)d_in[7]};
    const float* bls[3] = {(const float*)d_in[4], (const float*)d_in[6], (const float*)d_in[8]};
    const float* qws[2] = {(const float*)d_in[9], (const float*)d_in[13]};
    const float* qbs[2] = {(const float*)d_in[10], (const float*)d_in[14]};
    const float* kws[2] = {(const float*)d_in[11], (const float*)d_in[15]};
    const float* kbs[2] = {(const float*)d_in[12], (const float*)d_in[16]};

    char* base = (char*)d_ws;
    size_t cur = 0;
    auto alloc = [&](size_t bytes) -> void* {
        cur = (cur + 1023) & ~(size_t)1023;
        void* p = base + cur;
        cur += bytes;
        return p;
    };
    const size_t NROW = 16384;
    const size_t SEG = NROW * 256;  // 4194304 elements
    int* flags = (int*)alloc(12);
    unsigned char* pad = (unsigned char*)alloc(NROW);
    float* thr = (float*)alloc(256);
    unsigned* prefix = (unsigned*)alloc(256);
    int* krem = (int*)alloc(256);
    unsigned* ghist = (unsigned*)alloc(64 * 256 * 4);
    short* WTh = (short*)alloc((size_t)2304 * 256 * 2);
    short* WTl = (short*)alloc((size_t)2304 * 256 * 2);
    short* qkwPh = (short*)alloc((size_t)2 * 1024 * 1024 * 2);  // [half p][D rows][D]
    short* qkwPl = (short*)alloc((size_t)2 * 1024 * 1024 * 2);
    float* qkb = (float*)alloc((size_t)2 * 1024 * 4);
    short* xh = (short*)alloc(NROW * 1024 * 2);
    short* xl = (short*)alloc(NROW * 1024 * 2);
    float* a4 = (float*)alloc(4 * SEG * 4);  // 4 softmax partials; overlays a/tzf/a2f:
    short* QKh = (short*)alloc(NROW * 1024 * 2);  // one half Q|K [16384, D]
    short* QKl = (short*)alloc(NROW * 1024 * 2);
    if (ws_size < cur) return;  // clean failure instead of device fault

    float* a = a4;                // partial 0 (persists after add4)
    float* tzf = a4 + SEG;        // x@W fp32 (dead during attention)
    float* a2f = a4 + 3 * SEG;    // selected adjacency (dead during attention)
    const int Ks[3] = {512, 768, 1024};
    const long offW[3] = {0, (long)512 * 256, (long)(512 + 768) * 256};

    init_flags<<<1, 64, 0, stream>>>(flags);
    detect_mask<<<64, 256, 0, stream>>>((const unsigned int*)mask, 1048576, flags);
    extract_pad<<<64, 256, 0, stream>>>(mask, flags, pad);
    split_mat<<<16384, 256, 0, stream>>>(x0, 512, 512, xh, xl, 1024);
    for (int l = 0; l < 3; ++l)
        transpose_split<<<dim3(8, Ks[l] / 32), 256, 0, stream>>>(
            Wls[l], WTh + offW[l], WTl + offW[l], Ks[l], 256, 256, 0, 0, Ks[l]);

    for (int l = 0; l < 3; ++l) {
        int Kl = Ks[l];
        // tzf = x @ Wl (fp32 row-major; bias applied in spmm epilogue)
        mgemm<<<dim3(128, 2, 1), 256, 0, stream>>>(
            xh, xl, WTh + offW[l], WTl + offW[l], nullptr,
            tzf, nullptr, nullptr, nullptr, Kl, 1024, Kl, 256);
        // fused sparse GCN: out = relu((A@tz + b)/denom) + tz + b   (exact fp32)
        const float* Aadj = (l == 0) ? adj : a2f;
        if (l < 2) {
            spmm_gcn<<<4096, 256, 0, stream>>>(
                Aadj, tzf, bls[l], xh, xl, nullptr, 1024, Kl);
        } else {
            spmm_gcn<<<4096, 256, 0, stream>>>(
                Aadj, tzf, bls[l], nullptr, nullptr, (float*)d_out, 256, 0);
            break;
        }

        // ---- attention l (D = Ks[l+1], dk = D/8), two head-halves of 4 heads
        int D = Ks[l + 1], dk = D / 8, HD = D / 2;
        float scale = 1.f / sqrtf((float)dk);
        transpose_split<<<dim3(D / 32, D / 32), 256, 0, stream>>>(
            qws[l], qkwPh, qkwPl, D, D, HD, (long)D * D, 0, D);
        transpose_split<<<dim3(D / 32, D / 32), 256, 0, stream>>>(
            kws[l], qkwPh, qkwPl, D, D, HD, (long)D * D, HD, D);
        pack_bias2<<<4, 256, 0, stream>>>(qbs[l], kbs[l], qkb, D);

        for (int p = 0; p < 2; ++p) {
            // QK[:,0:HD]=Q(4 heads), QK[:,HD:D]=K(4 heads); pad m-tiles skipped.
            mgemm<<<dim3(128, D / 128, 1), 256, 0, stream>>>(
                xh, xl, qkwPh + (size_t)p * D * D, qkwPl + (size_t)p * D * D,
                qkb + (size_t)p * D, nullptr, QKh, QKl, pad, D, 1024, D, D);
            // fused scores+softmax+pair-sum into partials a4[p*2 + z]
            attn_fused<<<dim3(4, 64, 2), 256, 0, stream>>>(
                QKh, QKl, pad, a4 + (size_t)p * 2 * SEG, D, dk, scale);
        }
        add4<<<4096, 256, 0, stream>>>(a4, pad, a);
        tk_init<<<64, 256, 0, stream>>>(ghist, prefix, krem);
        for (int pp = 0; pp < 4; ++pp) {
            tk_hist<<<1024, 256, 0, stream>>>(a, prefix, ghist, 24 - 8 * pp);
            tk_pick<<<64, 256, 0, stream>>>(ghist, prefix, krem, thr, pp == 3);
        }
        select_apply<<<16384, 256, 0, stream>>>(a, thr, a2f);
    }
}